// Round 4
// baseline (659.036 us; speedup 1.0000x reference)
//
#include <hip/hip_runtime.h>
#include <math.h>

typedef __attribute__((ext_vector_type(8))) short bf16x8;
typedef __attribute__((ext_vector_type(4))) float f32x4;

#define BSZ 8
#define SEQ 2048
#define DIM 512
#define BS_TOT (BSZ*SEQ)

__device__ __forceinline__ unsigned short f2bf(float f) {
    unsigned int u = __float_as_uint(f);
    unsigned int r = (u + 0x7fffu + ((u >> 16) & 1u)) >> 16;
    return (unsigned short)r;
}

__device__ __forceinline__ f32x4 mfma16(bf16x8 a, bf16x8 b, f32x4 c) {
    return __builtin_amdgcn_mfma_f32_16x16x32_bf16(a, b, c, 0, 0, 0);
}

// Stage a [R rows x 64 cols] bf16 tile into LDS via async global_load_lds (16B/lane).
// XOR-swizzle: LDS[row][pchunk] = G[row][pchunk ^ (row&7)], pchunk = 16B chunk index.
// gbase points at G[row0][k0]; rstride = global row stride in elems. R multiple of 32.
#define STAGE64(gbase, rstride, ldsbase, R)                                        \
    {                                                                              \
        _Pragma("unroll")                                                          \
        for (int t_ = 0; t_ < (R) / 32; ++t_) {                                    \
            int r8_ = wave * ((R) / 32) + t_;                                      \
            int row_ = r8_ * 8 + (lane >> 3);                                      \
            int kch_ = (lane & 7) ^ (row_ & 7);                                    \
            const unsigned short* gp_ = (gbase) + (size_t)row_ * (rstride) + kch_ * 8; \
            __builtin_amdgcn_global_load_lds(                                      \
                (const __attribute__((address_space(1))) unsigned int*)gp_,        \
                (__attribute__((address_space(3))) unsigned int*)((ldsbase) + r8_ * 512), \
                16, 0, 0);                                                         \
        }                                                                          \
    }

// Read an A-operand fragment (row, logical 16B-chunk kc) from a swizzled LDS tile.
__device__ __forceinline__ bf16x8 frag_ld(const unsigned short* lds, int row, int kc) {
    return *(const bf16x8*)(lds + row * 64 + (((kc) ^ (row & 7)) << 3));
}

// ---------------- fp32 -> bf16 conversion (vector4) ----------------
__global__ __launch_bounds__(256) void conv_f2b(const float* __restrict__ src,
                                                unsigned short* __restrict__ dst, int n4) {
    int i = blockIdx.x * blockDim.x + threadIdx.x;
    if (i < n4) {
        float4 v = ((const float4*)src)[i];
        ushort4 o;
        o.x = f2bf(v.x); o.y = f2bf(v.y); o.z = f2bf(v.z); o.w = f2bf(v.w);
        ((ushort4*)dst)[i] = o;
    }
}

// ---------------- per-point attr table, packed 8 floats ----------------
__global__ __launch_bounds__(256) void trig_prep(const float* __restrict__ lat,
                                                 const float* __restrict__ lon,
                                                 const float* __restrict__ tm,
                                                 const int* __restrict__ mask,
                                                 float* __restrict__ trigp) {
    int i = blockIdx.x * blockDim.x + threadIdx.x;
    if (i < BS_TOT) {
        const float RAD = 0.017453292519943295f;
        float la = lat[i] * RAD, lo = lon[i] * RAD;
        float4 a = {sinf(la * 0.5f), cosf(la * 0.5f), sinf(lo * 0.5f), cosf(lo * 0.5f)};
        float4 b = {cosf(la), tm[i], mask[i] ? 1.0f : 0.0f, 0.0f};
        ((float4*)trigp)[(size_t)i * 2] = a;
        ((float4*)trigp)[(size_t)i * 2 + 1] = b;
    }
}

// ---------------- fused QKV projection GEMM ----------------
// A (x) staged via LDS; B (W) direct from global (L1/L2-resident).
__global__ __launch_bounds__(256) void qkv_gemm(
    const unsigned short* __restrict__ xb,
    const unsigned short* __restrict__ Wqb, const unsigned short* __restrict__ Wkb,
    const unsigned short* __restrict__ Wvb,
    const float* __restrict__ bq, const float* __restrict__ bk, const float* __restrict__ bv,
    unsigned short* __restrict__ Qb, unsigned short* __restrict__ Kb,
    unsigned short* __restrict__ VTb) {
    __shared__ __align__(16) unsigned short As[128 * 64];
    __shared__ __align__(16) unsigned short Ts[9216];

    const int tid = threadIdx.x;
    const int lane = tid & 63, wave = tid >> 6;
    const int lq = lane & 15, quad = lane >> 4;
    const int m0 = blockIdx.x * 128, n0 = blockIdx.y * 64;

    f32x4 acc[3][2][4];
    #pragma unroll
    for (int o = 0; o < 3; ++o)
        #pragma unroll
        for (int mi = 0; mi < 2; ++mi)
            #pragma unroll
            for (int c = 0; c < 4; ++c) acc[o][mi][c] = (f32x4){0.f, 0.f, 0.f, 0.f};

    const unsigned short* Ag = xb + (size_t)m0 * DIM;
    const unsigned short* Ws[3] = {Wqb, Wkb, Wvb};

    for (int kc = 0; kc < 8; ++kc) {
        __syncthreads();
        STAGE64(Ag + kc * 64, DIM, As, 128);
        __syncthreads();
        #pragma unroll
        for (int ks = 0; ks < 2; ++ks) {
            bf16x8 a0 = frag_ld(As, wave * 32 + lq, ks * 4 + quad);
            bf16x8 a1 = frag_ld(As, wave * 32 + 16 + lq, ks * 4 + quad);
            #pragma unroll
            for (int o = 0; o < 3; ++o) {
                const unsigned short* bb =
                    Ws[o] + (size_t)(n0 + lq) * DIM + kc * 64 + ks * 32 + quad * 8;
                #pragma unroll
                for (int c = 0; c < 4; ++c) {
                    bf16x8 bf = *(const bf16x8*)(bb + (size_t)c * 16 * DIM);
                    acc[o][0][c] = mfma16(a0, bf, acc[o][0][c]);
                    acc[o][1][c] = mfma16(a1, bf, acc[o][1][c]);
                }
            }
        }
    }

    const float* biases[3] = {bq, bk, bv};
    #pragma unroll
    for (int o = 0; o < 3; ++o) {
        __syncthreads();
        if (o < 2) {
            #pragma unroll
            for (int c = 0; c < 4; ++c) {
                float be = biases[o][n0 + c * 16 + lq];
                #pragma unroll
                for (int mi = 0; mi < 2; ++mi)
                    #pragma unroll
                    for (int r = 0; r < 4; ++r)
                        Ts[(wave * 32 + mi * 16 + quad * 4 + r) * 72 + c * 16 + lq] =
                            f2bf(acc[o][mi][c][r] + be);
            }
            __syncthreads();
            unsigned short* G = (o == 0) ? Qb : Kb;
            int mrow = tid >> 1, half = tid & 1;
            const unsigned short* lp = &Ts[mrow * 72 + half * 32];
            unsigned short* gp = G + (size_t)(m0 + mrow) * DIM + n0 + half * 32;
            #pragma unroll
            for (int u = 0; u < 4; ++u)
                *(uint4*)(gp + u * 8) = *(const uint4*)(lp + u * 8);
        } else {
            #pragma unroll
            for (int c = 0; c < 4; ++c) {
                float be = biases[2][n0 + c * 16 + lq];
                #pragma unroll
                for (int mi = 0; mi < 2; ++mi)
                    #pragma unroll
                    for (int r = 0; r < 4; ++r)
                        Ts[(c * 16 + lq) * 136 + wave * 32 + mi * 16 + quad * 4 + r] =
                            f2bf(acc[2][mi][c][r] + be);
            }
            __syncthreads();
            int e = tid >> 2, mq = tid & 3;
            const unsigned short* lp = &Ts[e * 136 + mq * 32];
            unsigned short* gp = VTb + ((size_t)(m0 >> 11) * DIM + n0 + e) * SEQ +
                                 (m0 & 2047) + mq * 32;
            #pragma unroll
            for (int u = 0; u < 4; ++u)
                *(uint4*)(gp + u * 8) = *(const uint4*)(lp + u * 8);
        }
    }
}

// ---------------- phase 1: 128x128 score tiles, tile-local softmax ----------------
// P' = exp(s - m_tile) bf16; Mc/Lc per (row, j-tile).
__global__ __launch_bounds__(256) void score_kernel(
    const unsigned short* __restrict__ Qb, const unsigned short* __restrict__ Kb,
    const float* __restrict__ trigp, unsigned short* __restrict__ Pbuf,
    float* __restrict__ Mc, float* __restrict__ Lc) {
    __shared__ __align__(16) unsigned short As[128 * 64];

    const int tid = threadIdx.x, lane = tid & 63, wave = tid >> 6;
    const int lq = lane & 15, quad = lane >> 4;
    const int it = blockIdx.x, jt = blockIdx.y, b = blockIdx.z;
    const int i0 = it * 128, j0 = jt * 128;
    const size_t rowQ = (size_t)b * SEQ + i0;
    const size_t rowK = (size_t)b * SEQ + j0;

    f32x4 acc[2][8];
    #pragma unroll
    for (int ms = 0; ms < 2; ++ms)
        #pragma unroll
        for (int cg = 0; cg < 8; ++cg) acc[ms][cg] = (f32x4){0.f, 0.f, 0.f, 0.f};

    const unsigned short* Ag = Qb + rowQ * DIM;
    const unsigned short* Bg = Kb + (rowK + lq) * DIM + quad * 8;

    for (int kc = 0; kc < 8; ++kc) {
        __syncthreads();
        STAGE64(Ag + kc * 64, DIM, As, 128);
        __syncthreads();
        #pragma unroll
        for (int ks = 0; ks < 2; ++ks) {
            bf16x8 a0 = frag_ld(As, wave * 32 + lq, ks * 4 + quad);
            bf16x8 a1 = frag_ld(As, wave * 32 + 16 + lq, ks * 4 + quad);
            #pragma unroll
            for (int cg = 0; cg < 8; ++cg) {
                bf16x8 bf = *(const bf16x8*)(Bg + (size_t)cg * 16 * DIM + kc * 64 + ks * 32);
                acc[0][cg] = mfma16(a0, bf, acc[0][cg]);
                acc[1][cg] = mfma16(a1, bf, acc[1][cg]);
            }
        }
    }

    // ---- epilogue: bias + mask + tile-local softmax ----
    const float scale = 0.04419417382415922f;   // 1/sqrt(512)
    float qa_sla[2][4], qa_cla[2][4], qa_slo[2][4], qa_clo[2][4], qa_ca[2][4], qa_t[2][4];
    #pragma unroll
    for (int ms = 0; ms < 2; ++ms)
        #pragma unroll
        for (int r = 0; r < 4; ++r) {
            const float4* tp =
                (const float4*)(trigp + (rowQ + wave * 32 + ms * 16 + quad * 4 + r) * 8);
            float4 t0 = tp[0], t1 = tp[1];
            qa_sla[ms][r] = t0.x; qa_cla[ms][r] = t0.y;
            qa_slo[ms][r] = t0.z; qa_clo[ms][r] = t0.w;
            qa_ca[ms][r] = t1.x; qa_t[ms][r] = t1.y;
        }

    float mt[2][4];
    #pragma unroll
    for (int ms = 0; ms < 2; ++ms)
        #pragma unroll
        for (int r = 0; r < 4; ++r) mt[ms][r] = -__builtin_inff();

    #pragma unroll
    for (int cg = 0; cg < 8; ++cg) {
        const float4* kp4 = (const float4*)(trigp + (rowK + cg * 16 + lq) * 8);
        float4 k0 = kp4[0], k1 = kp4[1];
        #pragma unroll
        for (int ms = 0; ms < 2; ++ms)
            #pragma unroll
            for (int r = 0; r < 4; ++r) {
                float sdlat = k0.x * qa_cla[ms][r] - k0.y * qa_sla[ms][r];
                float sdlon = k0.z * qa_clo[ms][r] - k0.w * qa_slo[ms][r];
                float aa = sdlat * sdlat + qa_ca[ms][r] * k1.x * (sdlon * sdlon);
                aa = fminf(fmaxf(aa, 0.f), 1.f);
                float sv = acc[ms][cg][r] * scale - 12742.0f * asinf(sqrtf(aa)) -
                           fabsf(k1.y - qa_t[ms][r]);
                sv = (k1.z != 0.0f) ? sv : -1e9f;
                acc[ms][cg][r] = sv;
                mt[ms][r] = fmaxf(mt[ms][r], sv);
            }
    }
    #pragma unroll
    for (int o = 1; o < 16; o <<= 1)
        #pragma unroll
        for (int ms = 0; ms < 2; ++ms)
            #pragma unroll
            for (int r = 0; r < 4; ++r) mt[ms][r] = fmaxf(mt[ms][r], __shfl_xor(mt[ms][r], o));

    float sm[2][4];
    #pragma unroll
    for (int ms = 0; ms < 2; ++ms)
        #pragma unroll
        for (int r = 0; r < 4; ++r) sm[ms][r] = 0.f;
    #pragma unroll
    for (int cg = 0; cg < 8; ++cg)
        #pragma unroll
        for (int ms = 0; ms < 2; ++ms)
            #pragma unroll
            for (int r = 0; r < 4; ++r) {
                float p = __expf(acc[ms][cg][r] - mt[ms][r]);
                acc[ms][cg][r] = p;
                sm[ms][r] += p;
            }
    #pragma unroll
    for (int o = 1; o < 16; o <<= 1)
        #pragma unroll
        for (int ms = 0; ms < 2; ++ms)
            #pragma unroll
            for (int r = 0; r < 4; ++r) sm[ms][r] += __shfl_xor(sm[ms][r], o);

    #pragma unroll
    for (int ms = 0; ms < 2; ++ms)
        #pragma unroll
        for (int cg = 0; cg < 8; ++cg)
            #pragma unroll
            for (int r = 0; r < 4; ++r)
                Pbuf[(rowQ + wave * 32 + ms * 16 + quad * 4 + r) * SEQ + j0 + cg * 16 + lq] =
                    f2bf(acc[ms][cg][r]);
    if (lq == 0) {
        #pragma unroll
        for (int ms = 0; ms < 2; ++ms)
            #pragma unroll
            for (int r = 0; r < 4; ++r) {
                size_t g = rowQ + wave * 32 + ms * 16 + quad * 4 + r;
                Mc[g * 16 + jt] = mt[ms][r];
                Lc[g * 16 + jt] = sm[ms][r];
            }
    }
}

// ---------------- phase 1.5: merge tile stats, scale P' in place ----------------
// One wave per row: M = max_c Mc, L = sum_c Lc*exp(Mc-M); P *= exp(Mc-M)/L per 128-chunk.
__global__ __launch_bounds__(256) void scale_kernel(
    const float* __restrict__ Mc, const float* __restrict__ Lc,
    unsigned short* __restrict__ Pbuf) {
    const int lane = threadIdx.x & 63, wave = threadIdx.x >> 6;
    const size_t g = (size_t)blockIdx.x * 4 + wave;
    const int c = lane & 15;
    float mc = Mc[g * 16 + c], lc = Lc[g * 16 + c];
    float M = mc;
    #pragma unroll
    for (int o = 1; o < 16; o <<= 1) M = fmaxf(M, __shfl_xor(M, o));
    float le = lc * __expf(mc - M);
    float L = le;
    #pragma unroll
    for (int o = 1; o < 16; o <<= 1) L += __shfl_xor(L, o);
    float sc = __expf(mc - M) / L;

    unsigned short* row = Pbuf + g * SEQ;
    #pragma unroll
    for (int u = 0; u < 4; ++u) {
        int idx = (u * 64 + lane) * 8;
        float s = __shfl(sc, idx >> 7, 16);
        bf16x8 v = *(const bf16x8*)(row + idx);
        bf16x8 o;
        #pragma unroll
        for (int e = 0; e < 8; ++e) {
            float f = __uint_as_float(((unsigned int)(unsigned short)v[e]) << 16);
            o[e] = (short)f2bf(f * s);
        }
        *(bf16x8*)(row + idx) = o;
    }
}

// ---------------- phase 2: pure GEMM O = P V ----------------
// A (P, scaled) staged via LDS; B (V^T) direct from global (L1/L2-resident).
__global__ __launch_bounds__(256) void pv_kernel(
    const unsigned short* __restrict__ Pbuf, const unsigned short* __restrict__ VTb,
    float* __restrict__ Out) {
    __shared__ __align__(16) unsigned short As[128 * 64];

    const int tid = threadIdx.x, lane = tid & 63, wave = tid >> 6;
    const int lq = lane & 15, quad = lane >> 4;
    const int it = blockIdx.x, dt = blockIdx.y, b = blockIdx.z;
    const int i0 = it * 128, d0 = dt * 64;

    f32x4 acc[2][4];
    #pragma unroll
    for (int ms = 0; ms < 2; ++ms)
        #pragma unroll
        for (int cg = 0; cg < 4; ++cg) acc[ms][cg] = (f32x4){0.f, 0.f, 0.f, 0.f};

    const unsigned short* Ag = Pbuf + ((size_t)b * SEQ + i0) * SEQ;
    const unsigned short* vp = VTb + ((size_t)b * DIM + d0 + lq) * SEQ + quad * 8;

    #pragma unroll 1
    for (int kc = 0; kc < 32; ++kc) {
        __syncthreads();
        STAGE64(Ag + kc * 64, SEQ, As, 128);
        __syncthreads();
        #pragma unroll
        for (int ks = 0; ks < 2; ++ks) {
            bf16x8 a0 = frag_ld(As, wave * 32 + lq, ks * 4 + quad);
            bf16x8 a1 = frag_ld(As, wave * 32 + 16 + lq, ks * 4 + quad);
            #pragma unroll
            for (int cg = 0; cg < 4; ++cg) {
                bf16x8 vf = *(const bf16x8*)(vp + (size_t)cg * 16 * SEQ + kc * 64 + ks * 32);
                acc[0][cg] = mfma16(a0, vf, acc[0][cg]);
                acc[1][cg] = mfma16(a1, vf, acc[1][cg]);
            }
        }
    }

    #pragma unroll
    for (int ms = 0; ms < 2; ++ms)
        #pragma unroll
        for (int r = 0; r < 4; ++r) {
            size_t orow = ((size_t)b * SEQ + i0 + wave * 32 + ms * 16 + quad * 4 + r) * DIM;
            #pragma unroll
            for (int cg = 0; cg < 4; ++cg)
                Out[orow + d0 + cg * 16 + lq] = acc[ms][cg][r];
        }
}

extern "C" void kernel_launch(void* const* d_in, const int* in_sizes, int n_in,
                              void* d_out, int out_size, void* d_ws, size_t ws_size,
                              hipStream_t stream) {
    (void)in_sizes; (void)n_in; (void)out_size; (void)ws_size;
    const float* x    = (const float*)d_in[0];
    const float* tseq = (const float*)d_in[1];
    const float* lat  = (const float*)d_in[2];
    const float* lon  = (const float*)d_in[3];
    const int*   mk   = (const int*)d_in[4];
    const float* Wq   = (const float*)d_in[5];
    const float* bq   = (const float*)d_in[6];
    const float* Wk   = (const float*)d_in[7];
    const float* bk   = (const float*)d_in[8];
    const float* Wv   = (const float*)d_in[9];
    const float* bv   = (const float*)d_in[10];
    float* out = (float*)d_out;

    unsigned short* xb  = (unsigned short*)d_ws;
    unsigned short* Qb  = xb + (size_t)BS_TOT * DIM;
    unsigned short* Kb  = Qb + (size_t)BS_TOT * DIM;
    unsigned short* VTb = Kb + (size_t)BS_TOT * DIM;
    unsigned short* Wqb = VTb + (size_t)BS_TOT * DIM;
    unsigned short* Wkb = Wqb + DIM * DIM;
    unsigned short* Wvb = Wkb + DIM * DIM;
    float* trigp = (float*)(Wvb + DIM * DIM);                  // 16384 x 8 f32
    unsigned short* Pbuf = (unsigned short*)(trigp + (size_t)BS_TOT * 8);  // 67 MB
    float* Mc = (float*)(Pbuf + (size_t)BS_TOT * SEQ);         // 16384 x 16
    float* Lc = Mc + (size_t)BS_TOT * 16;                      // 16384 x 16

    conv_f2b<<<(BS_TOT * DIM / 4 + 255) / 256, 256, 0, stream>>>(x, xb, BS_TOT * DIM / 4);
    conv_f2b<<<(DIM * DIM / 4 + 255) / 256, 256, 0, stream>>>(Wq, Wqb, DIM * DIM / 4);
    conv_f2b<<<(DIM * DIM / 4 + 255) / 256, 256, 0, stream>>>(Wk, Wkb, DIM * DIM / 4);
    conv_f2b<<<(DIM * DIM / 4 + 255) / 256, 256, 0, stream>>>(Wv, Wvb, DIM * DIM / 4);
    trig_prep<<<(BS_TOT + 255) / 256, 256, 0, stream>>>(lat, lon, tseq, mk, trigp);

    qkv_gemm<<<dim3(BS_TOT / 128, DIM / 64), 256, 0, stream>>>(
        xb, Wqb, Wkb, Wvb, bq, bk, bv, Qb, Kb, VTb);

    score_kernel<<<dim3(SEQ / 128, SEQ / 128, BSZ), 256, 0, stream>>>(
        Qb, Kb, trigp, Pbuf, Mc, Lc);
    scale_kernel<<<BS_TOT / 4, 256, 0, stream>>>(Mc, Lc, Pbuf);
    pv_kernel<<<dim3(SEQ / 128, DIM / 64, BSZ), 256, 0, stream>>>(Pbuf, VTb, out);
}

// Round 5
// 328.469 us; speedup vs baseline: 2.0064x; 2.0064x over previous
//
#include <hip/hip_runtime.h>
#include <math.h>

typedef __attribute__((ext_vector_type(8))) short bf16x8;
typedef __attribute__((ext_vector_type(4))) float f32x4;

#define BSZ 8
#define SEQ 2048
#define DIM 512
#define BS_TOT (BSZ*SEQ)

__device__ __forceinline__ unsigned short f2bf(float f) {
    unsigned int u = __float_as_uint(f);
    unsigned int r = (u + 0x7fffu + ((u >> 16) & 1u)) >> 16;
    return (unsigned short)r;
}

__device__ __forceinline__ f32x4 mfma16(bf16x8 a, bf16x8 b, f32x4 c) {
    return __builtin_amdgcn_mfma_f32_16x16x32_bf16(a, b, c, 0, 0, 0);
}

// Stage a [R rows x 64 cols] bf16 tile into LDS via async global_load_lds (16B/lane).
// XOR-swizzle: LDS slot c holds global chunk c ^ (row&7). R multiple of 32.
#define STAGE64(gbase, rstride, ldsbase, R)                                        \
    {                                                                              \
        _Pragma("unroll")                                                          \
        for (int t_ = 0; t_ < (R) / 32; ++t_) {                                    \
            int r8_ = wave * ((R) / 32) + t_;                                      \
            int row_ = r8_ * 8 + (lane >> 3);                                      \
            int kch_ = (lane & 7) ^ (row_ & 7);                                    \
            const unsigned short* gp_ = (gbase) + (size_t)row_ * (rstride) + kch_ * 8; \
            __builtin_amdgcn_global_load_lds(                                      \
                (const __attribute__((address_space(1))) unsigned int*)gp_,        \
                (__attribute__((address_space(3))) unsigned int*)((ldsbase) + r8_ * 512), \
                16, 0, 0);                                                         \
        }                                                                          \
    }

__device__ __forceinline__ bf16x8 frag_ld(const unsigned short* lds, int row, int kc) {
    return *(const bf16x8*)(lds + row * 64 + (((kc) ^ (row & 7)) << 3));
}

// ---------------- fp32 -> bf16 conversion ----------------
__global__ __launch_bounds__(256) void conv_f2b(const float* __restrict__ src,
                                                unsigned short* __restrict__ dst, int n4) {
    int i = blockIdx.x * blockDim.x + threadIdx.x;
    if (i < n4) {
        float4 v = ((const float4*)src)[i];
        ushort4 o;
        o.x = f2bf(v.x); o.y = f2bf(v.y); o.z = f2bf(v.z); o.w = f2bf(v.w);
        ((ushort4*)dst)[i] = o;
    }
}

// ---------------- per-point attr table, packed 8 floats ----------------
__global__ __launch_bounds__(256) void trig_prep(const float* __restrict__ lat,
                                                 const float* __restrict__ lon,
                                                 const float* __restrict__ tm,
                                                 const int* __restrict__ mask,
                                                 float* __restrict__ trigp) {
    int i = blockIdx.x * blockDim.x + threadIdx.x;
    if (i < BS_TOT) {
        const float RAD = 0.017453292519943295f;
        float la = lat[i] * RAD, lo = lon[i] * RAD;
        float4 a = {sinf(la * 0.5f), cosf(la * 0.5f), sinf(lo * 0.5f), cosf(lo * 0.5f)};
        float4 b = {cosf(la), tm[i], mask[i] ? 1.0f : 0.0f, 0.0f};
        ((float4*)trigp)[(size_t)i * 2] = a;
        ((float4*)trigp)[(size_t)i * 2 + 1] = b;
    }
}

// ---------------- QKV projection GEMM: one 128x128 tile of one output ----------------
// grid (BS_TOT/128, 12): y -> (o = y>>2, n0 = (y&3)*128)
__global__ __launch_bounds__(256, 3) void qkv_gemm(
    const unsigned short* __restrict__ xb,
    const unsigned short* __restrict__ Wqb, const unsigned short* __restrict__ Wkb,
    const unsigned short* __restrict__ Wvb,
    const float* __restrict__ bq, const float* __restrict__ bk, const float* __restrict__ bv,
    unsigned short* __restrict__ Qb, unsigned short* __restrict__ Kb,
    unsigned short* __restrict__ VTb) {
    __shared__ __align__(16) unsigned short As[128 * 64];
    __shared__ __align__(16) unsigned short Bs[128 * 64];

    const int tid = threadIdx.x, lane = tid & 63, wave = tid >> 6;
    const int lq = lane & 15, quad = lane >> 4;
    const int w0 = wave & 1, w1 = wave >> 1;
    const int m0 = blockIdx.x * 128;
    const int o = blockIdx.y >> 2, n0 = (blockIdx.y & 3) * 128;
    const unsigned short* W = (o == 0) ? Wqb : (o == 1) ? Wkb : Wvb;
    const float* bias = (o == 0) ? bq : (o == 1) ? bk : bv;

    f32x4 acc[4][4];
    #pragma unroll
    for (int mi = 0; mi < 4; ++mi)
        #pragma unroll
        for (int ni = 0; ni < 4; ++ni) acc[mi][ni] = (f32x4){0.f, 0.f, 0.f, 0.f};

    const unsigned short* Ag = xb + (size_t)m0 * DIM;
    const unsigned short* Bg = W + (size_t)n0 * DIM;

    for (int kc = 0; kc < 8; ++kc) {
        __syncthreads();
        STAGE64(Ag + kc * 64, DIM, As, 128);
        STAGE64(Bg + kc * 64, DIM, Bs, 128);
        __syncthreads();
        #pragma unroll
        for (int ks = 0; ks < 2; ++ks) {
            bf16x8 af[4], bfr[4];
            #pragma unroll
            for (int mi = 0; mi < 4; ++mi) af[mi] = frag_ld(As, w0 * 64 + mi * 16 + lq, ks * 4 + quad);
            #pragma unroll
            for (int ni = 0; ni < 4; ++ni) bfr[ni] = frag_ld(Bs, w1 * 64 + ni * 16 + lq, ks * 4 + quad);
            #pragma unroll
            for (int mi = 0; mi < 4; ++mi)
                #pragma unroll
                for (int ni = 0; ni < 4; ++ni)
                    acc[mi][ni] = mfma16(af[mi], bfr[ni], acc[mi][ni]);
        }
    }

    if (o < 2) {
        unsigned short* G = (o == 0) ? Qb : Kb;
        #pragma unroll
        for (int ni = 0; ni < 4; ++ni) {
            int e = n0 + w1 * 64 + ni * 16 + lq;
            float be = bias[e];
            #pragma unroll
            for (int mi = 0; mi < 4; ++mi)
                #pragma unroll
                for (int r = 0; r < 4; ++r) {
                    int mrow = m0 + w0 * 64 + mi * 16 + quad * 4 + r;
                    G[(size_t)mrow * DIM + e] = f2bf(acc[mi][ni][r] + be);
                }
        }
    } else {
        #pragma unroll
        for (int ni = 0; ni < 4; ++ni) {
            int e = n0 + w1 * 64 + ni * 16 + lq;
            float be = bias[e];
            #pragma unroll
            for (int mi = 0; mi < 4; ++mi)
                #pragma unroll
                for (int r = 0; r < 4; ++r) {
                    int sg = m0 + w0 * 64 + mi * 16 + quad * 4 + r;
                    VTb[((size_t)(sg >> 11) * DIM + e) * SEQ + (sg & 2047)] =
                        f2bf(acc[mi][ni][r] + be);
                }
        }
    }
}

// ---------------- phase 1: 128x128 score tile, 64-col-local softmax ----------------
// P' = exp(s - m_64chunk); Mc/Lc per (row, 64-key chunk) [32 chunks/row].
__global__ __launch_bounds__(256, 3) void score_kernel(
    const unsigned short* __restrict__ Qb, const unsigned short* __restrict__ Kb,
    const float* __restrict__ trigp, unsigned short* __restrict__ Pbuf,
    float* __restrict__ Mc, float* __restrict__ Lc) {
    __shared__ __align__(16) unsigned short As[128 * 64];
    __shared__ __align__(16) unsigned short Bs[128 * 64];

    const int tid = threadIdx.x, lane = tid & 63, wave = tid >> 6;
    const int lq = lane & 15, quad = lane >> 4;
    const int w0 = wave & 1, w1 = wave >> 1;
    const int it = blockIdx.x, jt = blockIdx.y, b = blockIdx.z;
    const int i0 = it * 128, j0 = jt * 128;
    const size_t rowQ = (size_t)b * SEQ + i0;
    const size_t rowK = (size_t)b * SEQ + j0;

    f32x4 acc[4][4];
    #pragma unroll
    for (int mi = 0; mi < 4; ++mi)
        #pragma unroll
        for (int ni = 0; ni < 4; ++ni) acc[mi][ni] = (f32x4){0.f, 0.f, 0.f, 0.f};

    const unsigned short* Ag = Qb + rowQ * DIM;
    const unsigned short* Bg = Kb + rowK * DIM;

    for (int kc = 0; kc < 8; ++kc) {
        __syncthreads();
        STAGE64(Ag + kc * 64, DIM, As, 128);
        STAGE64(Bg + kc * 64, DIM, Bs, 128);
        __syncthreads();
        #pragma unroll
        for (int ks = 0; ks < 2; ++ks) {
            bf16x8 af[4], bfr[4];
            #pragma unroll
            for (int mi = 0; mi < 4; ++mi) af[mi] = frag_ld(As, w0 * 64 + mi * 16 + lq, ks * 4 + quad);
            #pragma unroll
            for (int ni = 0; ni < 4; ++ni) bfr[ni] = frag_ld(Bs, w1 * 64 + ni * 16 + lq, ks * 4 + quad);
            #pragma unroll
            for (int mi = 0; mi < 4; ++mi)
                #pragma unroll
                for (int ni = 0; ni < 4; ++ni)
                    acc[mi][ni] = mfma16(af[mi], bfr[ni], acc[mi][ni]);
        }
    }

    // ---- pass 1: bias + mask, track row max (per 64-col wave tile) ----
    const float scale = 0.04419417382415922f;   // 1/sqrt(512)
    float mt[16];
    #pragma unroll
    for (int i = 0; i < 16; ++i) mt[i] = -__builtin_inff();

    #pragma unroll
    for (int mi = 0; mi < 4; ++mi) {
        float q_sla[4], q_cla[4], q_slo[4], q_clo[4], q_ca[4], q_t[4];
        #pragma unroll
        for (int r = 0; r < 4; ++r) {
            const float4* tp =
                (const float4*)(trigp + (rowQ + w0 * 64 + mi * 16 + quad * 4 + r) * 8);
            float4 t0 = tp[0], t1 = tp[1];
            q_sla[r] = t0.x; q_cla[r] = t0.y; q_slo[r] = t0.z; q_clo[r] = t0.w;
            q_ca[r] = t1.x; q_t[r] = t1.y;
        }
        #pragma unroll
        for (int ni = 0; ni < 4; ++ni) {
            const float4* kp = (const float4*)(trigp + (rowK + w1 * 64 + ni * 16 + lq) * 8);
            float4 k0 = kp[0], k1 = kp[1];
            #pragma unroll
            for (int r = 0; r < 4; ++r) {
                float sdlat = k0.x * q_cla[r] - k0.y * q_sla[r];
                float sdlon = k0.z * q_clo[r] - k0.w * q_slo[r];
                float aa = sdlat * sdlat + q_ca[r] * k1.x * (sdlon * sdlon);
                aa = fminf(fmaxf(aa, 0.f), 1.f);
                float sv = acc[mi][ni][r] * scale - 12742.0f * asinf(sqrtf(aa)) -
                           fabsf(k1.y - q_t[r]);
                sv = (k1.z != 0.0f) ? sv : -1e9f;
                acc[mi][ni][r] = sv;
                mt[mi * 4 + r] = fmaxf(mt[mi * 4 + r], sv);
            }
        }
    }
    #pragma unroll
    for (int o = 1; o < 16; o <<= 1)
        #pragma unroll
        for (int i = 0; i < 16; ++i) mt[i] = fmaxf(mt[i], __shfl_xor(mt[i], o));

    // ---- pass 2: exp, sum, store ----
    float sm[16];
    #pragma unroll
    for (int i = 0; i < 16; ++i) sm[i] = 0.f;
    #pragma unroll
    for (int mi = 0; mi < 4; ++mi)
        #pragma unroll
        for (int ni = 0; ni < 4; ++ni)
            #pragma unroll
            for (int r = 0; r < 4; ++r) {
                float p = __expf(acc[mi][ni][r] - mt[mi * 4 + r]);
                sm[mi * 4 + r] += p;
                Pbuf[(rowQ + w0 * 64 + mi * 16 + quad * 4 + r) * SEQ + j0 + w1 * 64 +
                     ni * 16 + lq] = f2bf(p);
            }
    #pragma unroll
    for (int o = 1; o < 16; o <<= 1)
        #pragma unroll
        for (int i = 0; i < 16; ++i) sm[i] += __shfl_xor(sm[i], o);

    if (lq == 0) {
        int chunk = jt * 2 + w1;
        #pragma unroll
        for (int mi = 0; mi < 4; ++mi)
            #pragma unroll
            for (int r = 0; r < 4; ++r) {
                size_t g = rowQ + w0 * 64 + mi * 16 + quad * 4 + r;
                Mc[g * 32 + chunk] = mt[mi * 4 + r];
                Lc[g * 32 + chunk] = sm[mi * 4 + r];
            }
    }
}

// ---------------- phase 1.5: per-row stats -> per-chunk scales ----------------
__global__ __launch_bounds__(256) void scstats(
    const float* __restrict__ Mc, const float* __restrict__ Lc,
    float* __restrict__ Sc) {
    int g = blockIdx.x * 256 + threadIdx.x;
    if (g >= BS_TOT) return;
    float M = -__builtin_inff();
    #pragma unroll
    for (int c = 0; c < 32; ++c) M = fmaxf(M, Mc[(size_t)g * 32 + c]);
    float L = 0.f;
    #pragma unroll
    for (int c = 0; c < 32; ++c) L += Lc[(size_t)g * 32 + c] * __expf(Mc[(size_t)g * 32 + c] - M);
    float invL = 1.0f / L;
    int b = g >> 11, i = g & 2047;
    #pragma unroll
    for (int c = 0; c < 32; ++c)
        Sc[((size_t)b * 32 + c) * SEQ + i] = __expf(Mc[(size_t)g * 32 + c] - M) * invL;
}

// ---------------- phase 2: O = sum_c Sc[c] * (P'_c V_c) ----------------
// Block 128x64 tile; wave = 32 rows x 64 cols. 32 K-iters of 64 keys.
__global__ __launch_bounds__(256, 4) void pv_kernel(
    const unsigned short* __restrict__ Pbuf, const unsigned short* __restrict__ VTb,
    const float* __restrict__ Sc, float* __restrict__ Out) {
    __shared__ __align__(16) unsigned short As[128 * 64];
    __shared__ __align__(16) unsigned short Bs[64 * 64];

    const int tid = threadIdx.x, lane = tid & 63, wave = tid >> 6;
    const int lq = lane & 15, quad = lane >> 4;
    const int i0 = blockIdx.x * 128, d0 = blockIdx.y * 64, b = blockIdx.z;

    f32x4 acc[2][4];
    #pragma unroll
    for (int mi = 0; mi < 2; ++mi)
        #pragma unroll
        for (int ni = 0; ni < 4; ++ni) acc[mi][ni] = (f32x4){0.f, 0.f, 0.f, 0.f};

    const unsigned short* Ag = Pbuf + ((size_t)b * SEQ + i0) * SEQ;
    const unsigned short* Bg = VTb + ((size_t)b * DIM + d0) * SEQ;

    #pragma unroll 1
    for (int kc = 0; kc < 32; ++kc) {
        __syncthreads();
        STAGE64(Ag + kc * 64, SEQ, As, 128);
        STAGE64(Bg + kc * 64, SEQ, Bs, 64);
        __syncthreads();
        f32x4 pacc[2][4];
        #pragma unroll
        for (int ks = 0; ks < 2; ++ks) {
            bf16x8 af[2], bfr[4];
            #pragma unroll
            for (int mi = 0; mi < 2; ++mi) af[mi] = frag_ld(As, wave * 32 + mi * 16 + lq, ks * 4 + quad);
            #pragma unroll
            for (int ni = 0; ni < 4; ++ni) bfr[ni] = frag_ld(Bs, ni * 16 + lq, ks * 4 + quad);
            #pragma unroll
            for (int mi = 0; mi < 2; ++mi)
                #pragma unroll
                for (int ni = 0; ni < 4; ++ni)
                    pacc[mi][ni] = (ks == 0)
                        ? mfma16(af[mi], bfr[ni], (f32x4){0.f, 0.f, 0.f, 0.f})
                        : mfma16(af[mi], bfr[ni], pacc[mi][ni]);
        }
        #pragma unroll
        for (int mi = 0; mi < 2; ++mi)
            #pragma unroll
            for (int r = 0; r < 4; ++r) {
                float s = Sc[((size_t)b * 32 + kc) * SEQ + i0 + wave * 32 + mi * 16 +
                             quad * 4 + r];
                #pragma unroll
                for (int ni = 0; ni < 4; ++ni) acc[mi][ni][r] += s * pacc[mi][ni][r];
            }
    }

    #pragma unroll
    for (int mi = 0; mi < 2; ++mi)
        #pragma unroll
        for (int r = 0; r < 4; ++r) {
            size_t orow = ((size_t)b * SEQ + i0 + wave * 32 + mi * 16 + quad * 4 + r) * DIM;
            #pragma unroll
            for (int ni = 0; ni < 4; ++ni)
                Out[orow + d0 + ni * 16 + lq] = acc[mi][ni][r];
        }
}

extern "C" void kernel_launch(void* const* d_in, const int* in_sizes, int n_in,
                              void* d_out, int out_size, void* d_ws, size_t ws_size,
                              hipStream_t stream) {
    (void)in_sizes; (void)n_in; (void)out_size; (void)ws_size;
    const float* x    = (const float*)d_in[0];
    const float* tseq = (const float*)d_in[1];
    const float* lat  = (const float*)d_in[2];
    const float* lon  = (const float*)d_in[3];
    const int*   mk   = (const int*)d_in[4];
    const float* Wq   = (const float*)d_in[5];
    const float* bq   = (const float*)d_in[6];
    const float* Wk   = (const float*)d_in[7];
    const float* bk   = (const float*)d_in[8];
    const float* Wv   = (const float*)d_in[9];
    const float* bv   = (const float*)d_in[10];
    float* out = (float*)d_out;

    unsigned short* xb  = (unsigned short*)d_ws;
    unsigned short* Qb  = xb + (size_t)BS_TOT * DIM;
    unsigned short* Kb  = Qb + (size_t)BS_TOT * DIM;
    unsigned short* VTb = Kb + (size_t)BS_TOT * DIM;
    unsigned short* Wqb = VTb + (size_t)BS_TOT * DIM;
    unsigned short* Wkb = Wqb + DIM * DIM;
    unsigned short* Wvb = Wkb + DIM * DIM;
    float* trigp = (float*)(Wvb + DIM * DIM);                  // 16384 x 8 f32
    unsigned short* Pbuf = (unsigned short*)(trigp + (size_t)BS_TOT * 8);  // 67 MB
    float* Mc = (float*)(Pbuf + (size_t)BS_TOT * SEQ);         // 16384 x 32
    float* Lc = Mc + (size_t)BS_TOT * 32;                      // 16384 x 32
    float* Sc = Lc + (size_t)BS_TOT * 32;                      // 8 x 32 x 2048

    conv_f2b<<<(BS_TOT * DIM / 4 + 255) / 256, 256, 0, stream>>>(x, xb, BS_TOT * DIM / 4);
    conv_f2b<<<(DIM * DIM / 4 + 255) / 256, 256, 0, stream>>>(Wq, Wqb, DIM * DIM / 4);
    conv_f2b<<<(DIM * DIM / 4 + 255) / 256, 256, 0, stream>>>(Wk, Wkb, DIM * DIM / 4);
    conv_f2b<<<(DIM * DIM / 4 + 255) / 256, 256, 0, stream>>>(Wv, Wvb, DIM * DIM / 4);
    trig_prep<<<(BS_TOT + 255) / 256, 256, 0, stream>>>(lat, lon, tseq, mk, trigp);

    qkv_gemm<<<dim3(BS_TOT / 128, 12), 256, 0, stream>>>(
        xb, Wqb, Wkb, Wvb, bq, bk, bv, Qb, Kb, VTb);

    score_kernel<<<dim3(SEQ / 128, SEQ / 128, BSZ), 256, 0, stream>>>(
        Qb, Kb, trigp, Pbuf, Mc, Lc);
    scstats<<<(BS_TOT + 255) / 256, 256, 0, stream>>>(Mc, Lc, Sc);
    pv_kernel<<<dim3(SEQ / 128, DIM / 64, BSZ), 256, 0, stream>>>(Pbuf, VTb, Sc, out);
}